// Round 4
// baseline (142.441 us; speedup 1.0000x reference)
//
#include <hip/hip_runtime.h>
#include <hip/hip_bf16.h>

#define N_   1024
#define E_   2048
#define W_   (2 * E_ + N_)   // 5120 columns
#define SIG_ 64
#define ROWS_ (N_ + 2 * E_)  // 5120 rows

union V8 {
    float  f[8];
    float4 q[2];
};

__global__ __launch_bounds__(256) void coeff_kernel(
    const float* __restrict__ M,        // [N_, E_] f32
    const float* __restrict__ params,   // [E_] f32
    const float* __restrict__ sw,       // [E_, SIG_] f32
    const int*   __restrict__ kinds,    // [E_] i32
    const int*   __restrict__ time_p,   // scalar (int payload or float bits)
    float*       __restrict__ out)      // [ROWS_, W_] f32
{
    const int idx = blockIdx.x * 256 + threadIdx.x;  // one thread = 8 f32 out
    const int row = idx / (W_ / 8);
    const int c0  = (idx - row * (W_ / 8)) * 8;

    V8 v;
#pragma unroll
    for (int j = 0; j < 8; ++j) v.f[j] = 0.0f;

    if (row < N_) {
        // kcl block: [M | 0 | 0]
        if (c0 < E_) {
            v.q[0] = *reinterpret_cast<const float4*>(M + row * E_ + c0);
            v.q[1] = *reinterpret_cast<const float4*>(M + row * E_ + c0 + 4);
        }
    } else if (row < N_ + E_) {
        // kvl block: [0 | I | -M^T]
        const int e = row - N_;
        if (c0 >= 2 * E_) {
            const int n0 = c0 - 2 * E_;
#pragma unroll
            for (int j = 0; j < 8; ++j)
                v.f[j] = 0.0f - M[(size_t)(n0 + j) * E_ + e];
        } else {
            const int d = (E_ + e) - c0;                 // identity at col E_+e
            if (d >= 0 && d < 8) v.f[d] = 1.0f;
        }
    } else {
        // elem block: [diag(z) | diag(y) | 0]
        const int e  = row - (N_ + E_);
        const int dz = e - c0;
        const int dy = (E_ + e) - c0;
        const bool hz = (dz >= 0) && (dz < 8);
        const bool hy = (dy >= 0) && (dy < 8);
        if (hz || hy) {
            const int   kind = kinds[e];
            const float p    = params[e];

            // robust time read: accept int32 payload or float32 bit pattern
            int t = *time_p;
            if ((unsigned)t >= (unsigned)SIG_) {
                union { int i; float f; } tu; tu.i = t;
                t = (int)tu.f;
                if ((unsigned)t >= (unsigned)SIG_) t = 0;
            }
            const bool  sw_on = sw[e * SIG_ + t] > 0.0f;  // sigmoid(x)>0.5 <=> x>0
            const float ndt   = -1e-6f / p;
            float z, y;
            switch (kind) {
                case 0:  z = -p;                  y = 1.0f;                break; // R
                case 1:  z = 0.0f;                y = 1.0f;                break; // IVS
                case 2:  z = 1.0f;                y = 0.0f;                break; // VC
                case 3:  z = sw_on ? 0.0f : 1.0f; y = sw_on ? 1.0f : 0.0f; break; // SW
                case 4:  z = ndt;                 y = 1.0f;                break; // C
                default: z = 1.0f;                y = ndt;                 break; // L
            }
            if (hz) v.f[dz] = z;
            if (hy) v.f[dy] = y;
        }
    }

    float* dst = out + (size_t)row * W_ + c0;
    *reinterpret_cast<float4*>(dst)     = v.q[0];
    *reinterpret_cast<float4*>(dst + 4) = v.q[1];
}

extern "C" void kernel_launch(void* const* d_in, const int* in_sizes, int n_in,
                              void* d_out, int out_size, void* d_ws, size_t ws_size,
                              hipStream_t stream) {
    const float* M      = (const float*)d_in[0];
    const float* params = (const float*)d_in[1];
    const float* sw     = (const float*)d_in[2];
    const int*   kinds  = (const int*)d_in[3];
    const int*   time_p = (const int*)d_in[4];
    float* out          = (float*)d_out;

    const int total_threads = (ROWS_ * W_) / 8;   // 3,276,800
    const int block = 256;
    const int grid  = total_threads / block;      // 12,800
    coeff_kernel<<<grid, block, 0, stream>>>(M, params, sw, kinds, time_p, out);
}